// Round 6
// baseline (625.977 us; speedup 1.0000x reference)
//
#include <hip/hip_runtime.h>
#include <hip/hip_cooperative_groups.h>

namespace cg = cooperative_groups;

constexpr int DEG = 32;
constexpr int BLOCKS = 256;    // R6: 64 -> 256 (1 block/CU; 4x TLP on latency-bound passes)
constexpr int THREADS = 256;
constexpr int SOLO_MAX = 64;   // frontier sizes handled by block 0 alone

// ---------------------------------------------------------------------------
// Per-source-node stable sort of the 32 outgoing edges by rotation error.
// Replicates lexsort((err, src)) — src blocks contiguous, stable tie-break.
// ---------------------------------------------------------------------------
__global__ void sort_edges_kernel(const float* __restrict__ eattr,
                                  const int* __restrict__ dst,
                                  int* __restrict__ nbr,
                                  int* __restrict__ eidx,
                                  int E) {
    __shared__ float serr[256];
    int e = blockIdx.x * 256 + threadIdx.x;
    float err = 1e30f;
    if (e < E) {
        float w = fabsf(eattr[e * 4 + 0]);
        w = fminf(w, 1.0f);
        float a = acosf(w);
        err = 2.0f * (a * 57.29577951308232f);
    }
    serr[threadIdx.x] = err;
    __syncthreads();
    if (e < E) {
        int s = e & (DEG - 1);
        int base = (int)threadIdx.x - s;
        int rank = 0;
        for (int t = 0; t < DEG; ++t) {
            float et = serr[base + t];
            rank += (int)((et < err) || (et == err && t < s));
        }
        int u = e >> 5;
        nbr[(u << 5) + rank] = dst[e];
        eidx[(u << 5) + rank] = e;
    }
}

// Coherent (L1-bypassing) read of a claim word. Needed wherever an atomicMin
// and a read of the same location sit in the same sync region: CDNA atomics
// update L2 only, and __syncthreads does NOT invalidate L1 (grid.sync does).
__device__ __forceinline__ int claim_ld(const int* p) {
    return __hip_atomic_load(p, __ATOMIC_RELAXED, __HIP_MEMORY_SCOPE_AGENT);
}

// ---------------------------------------------------------------------------
// Level-synchronous BFS, exact sequential semantics via claim key
// (parent_queue_pos<<5)|slot + in-order append. Sync-minimized:
//  - F <= SOLO_MAX: block 0 chews levels alone (__syncthreads only), 1 grid
//    sync per burst; claim reads are L1-bypassing (see claim_ld).
//  - else 2 grid syncs/level: [claims] sync [wins+lookback-scan+append] sync.
// ---------------------------------------------------------------------------
__global__ void __launch_bounds__(THREADS)
bfs_kernel(const float* __restrict__ eattr,
           const int* __restrict__ nbr,
           const int* __restrict__ eidx,
           int* __restrict__ queue,
           int* __restrict__ visited,
           int* __restrict__ claim,
           int* __restrict__ offs,
           unsigned int* __restrict__ state,  // lookback state, one per block
           int* __restrict__ ctrl,            // [0]=total, [1]=head, [2]=tail
           float* __restrict__ out,           // [0]=start, [1..]=quat[N][4]
           const int* __restrict__ startp,
           int N) {
    cg::grid_group grid = cg::this_grid();
    const int tid = blockIdx.x * blockDim.x + threadIdx.x;
    const int T = gridDim.x * blockDim.x;
    float* quat = out + 1;
    const int start = *startp;

    __shared__ int s_wsum[THREADS / 64];
    __shared__ int s_wbase[THREADS / 64];
    __shared__ int s_carry;
    __shared__ int s_excl;
    __shared__ int s_total;

    // init (everything is re-poisoned before every launch)
    for (int v = tid; v < N; v += T) {
        visited[v] = (v == start) ? 1 : 0;
        claim[v] = 0x7FFFFFFF;
        quat[4 * v + 0] = 1.0f;
        quat[4 * v + 1] = 0.0f;
        quat[4 * v + 2] = 0.0f;
        quat[4 * v + 3] = 0.0f;
    }
    if (tid == 0) {
        queue[0] = start;
        out[0] = (float)start;
    }
    grid.sync();

    int head = 0, tail = 1;
    while (head < tail) {
        const int F = tail - head;

        if (F <= SOLO_MAX) {
            // ---- solo burst: block 0 processes levels until F grows ----
            if (blockIdx.x == 0) {
                int h = head, t = tail;
                while (h < t && (t - h) <= SOLO_MAX) {
                    const int Fb = t - h;
                    for (int e = threadIdx.x; e < Fb * DEG; e += THREADS) {
                        int p = h + (e >> 5), s = e & 31;
                        int u = queue[p];
                        int v = nbr[(u << 5) + s];
                        if (!visited[v]) atomicMin(&claim[v], (p << 5) + s);
                    }
                    __syncthreads();
                    int my_c = 0;
                    if ((int)threadIdx.x < Fb) {
                        int p = h + (int)threadIdx.x, u = queue[p];
                        for (int s = 0; s < DEG; ++s) {
                            int v = nbr[(u << 5) + s];
                            if (!visited[v] && claim_ld(&claim[v]) == ((p << 5) + s)) my_c++;
                        }
                    }
                    int incl = my_c;
                    for (int d = 1; d < 64; d <<= 1) {
                        int tt = __shfl_up(incl, d, 64);
                        if ((threadIdx.x & 63) >= (unsigned)d) incl += tt;
                    }
                    if (threadIdx.x == 63) s_total = incl;
                    __syncthreads();
                    int total = s_total;
                    if ((int)threadIdx.x < Fb) {
                        int i = threadIdx.x;
                        int p = h + i, u = queue[p];
                        int pos = t + (incl - my_c);
                        float pw = quat[4 * u + 0], px = quat[4 * u + 1];
                        float py = quat[4 * u + 2], pz = quat[4 * u + 3];
                        for (int s = 0; s < DEG; ++s) {
                            int v = nbr[(u << 5) + s];
                            if (!visited[v] && claim_ld(&claim[v]) == ((p << 5) + s)) {
                                int eo = eidx[(u << 5) + s];
                                float qw = eattr[4 * eo + 0];
                                float qx = -eattr[4 * eo + 1];
                                float qy = -eattr[4 * eo + 2];
                                float qz = -eattr[4 * eo + 3];
                                quat[4 * v + 0] = qw * pw - qx * px - qy * py - qz * pz;
                                quat[4 * v + 1] = qw * px + qx * pw + qy * pz - qz * py;
                                quat[4 * v + 2] = qw * py - qx * pz + qy * pw + qz * px;
                                quat[4 * v + 3] = qw * pz + qx * py - qy * px + qz * pw;
                                visited[v] = 1;
                                queue[pos++] = v;
                            }
                        }
                    }
                    __syncthreads();
                    h = t;
                    t += total;
                }
                if (threadIdx.x == 0) { ctrl[1] = h; ctrl[2] = t; }
            }
            grid.sync();
            head = ctrl[1];
            tail = ctrl[2];
        } else {
            // ---- grid level, 2 syncs ----
            // pass 1: claims (+ reset own lookback slot)
            if (threadIdx.x == 0) state[blockIdx.x] = 0u;
            for (int e = tid; e < F * DEG; e += T) {
                int p = head + (e >> 5), s = e & 31;
                int u = queue[p];
                int v = nbr[(u << 5) + s];
                if (!visited[v]) atomicMin(&claim[v], (p << 5) + s);
            }
            grid.sync();

            // fused: wins + block-local scan + decoupled lookback + append
            const int CH = (F + BLOCKS - 1) / BLOCKS;
            const int c0 = blockIdx.x * CH;
            const int c1 = min(F, c0 + CH);
            if (threadIdx.x == 0) s_carry = 0;
            __syncthreads();
            for (int base = c0; base < c1; base += THREADS) {
                int i = base + (int)threadIdx.x;
                int x = 0;
                if (i < c1) {
                    int p = head + i, u = queue[p];
                    for (int s = 0; s < DEG; ++s) {
                        int v = nbr[(u << 5) + s];
                        if (!visited[v] && claim[v] == ((p << 5) + s)) x++;
                    }
                }
                int lane = threadIdx.x & 63, wid = threadIdx.x >> 6;
                int incl = x;
                for (int d = 1; d < 64; d <<= 1) {
                    int tt = __shfl_up(incl, d, 64);
                    if (lane >= d) incl += tt;
                }
                if (lane == 63) s_wsum[wid] = incl;
                __syncthreads();
                if (threadIdx.x == 0) {
                    int acc = s_carry;
                    for (int w = 0; w < THREADS / 64; ++w) {
                        s_wbase[w] = acc;
                        acc += s_wsum[w];
                    }
                    s_carry = acc;
                }
                __syncthreads();
                if (i < c1) offs[i] = s_wbase[wid] + incl - x;
                __syncthreads();
            }
            const int agg = s_carry;

            if (threadIdx.x == 0) {
                int sum = 0;
                if (blockIdx.x == 0) {
                    __hip_atomic_store(&state[0], 0x80000000u | (unsigned)agg,
                                       __ATOMIC_RELEASE, __HIP_MEMORY_SCOPE_AGENT);
                } else {
                    __hip_atomic_store(&state[blockIdx.x], 0x40000000u | (unsigned)agg,
                                       __ATOMIC_RELEASE, __HIP_MEMORY_SCOPE_AGENT);
                    for (int j = blockIdx.x - 1;;) {
                        unsigned int sv;
                        do {
                            sv = __hip_atomic_load(&state[j], __ATOMIC_ACQUIRE,
                                                   __HIP_MEMORY_SCOPE_AGENT);
                        } while ((sv & 0xC0000000u) == 0u);
                        sum += (int)(sv & 0x3FFFFFFFu);
                        if (sv & 0x80000000u) break;
                        --j;
                    }
                    __hip_atomic_store(&state[blockIdx.x],
                                       0x80000000u | (unsigned)(sum + agg),
                                       __ATOMIC_RELEASE, __HIP_MEMORY_SCOPE_AGENT);
                }
                s_excl = sum;
                if (blockIdx.x == BLOCKS - 1) ctrl[0] = sum + agg;
            }
            __syncthreads();
            const int excl = s_excl;

            for (int i = c0 + (int)threadIdx.x; i < c1; i += THREADS) {
                int p = head + i, u = queue[p];
                int pos = tail + excl + offs[i];
                float pw = quat[4 * u + 0], px = quat[4 * u + 1];
                float py = quat[4 * u + 2], pz = quat[4 * u + 3];
                for (int s = 0; s < DEG; ++s) {
                    int v = nbr[(u << 5) + s];
                    if (!visited[v] && claim[v] == ((p << 5) + s)) {
                        int eo = eidx[(u << 5) + s];
                        float qw = eattr[4 * eo + 0];
                        float qx = -eattr[4 * eo + 1];
                        float qy = -eattr[4 * eo + 2];
                        float qz = -eattr[4 * eo + 3];
                        quat[4 * v + 0] = qw * pw - qx * px - qy * py - qz * pz;
                        quat[4 * v + 1] = qw * px + qx * pw + qy * pz - qz * py;
                        quat[4 * v + 2] = qw * py - qx * pz + qy * pw + qz * px;
                        quat[4 * v + 3] = qw * pz + qx * py - qy * px + qz * pw;
                        visited[v] = 1;
                        queue[pos++] = v;
                    }
                }
            }
            grid.sync();
            head = tail;
            tail += ctrl[0];
        }
    }
}

extern "C" void kernel_launch(void* const* d_in, const int* in_sizes, int n_in,
                              void* d_out, int out_size, void* d_ws, size_t ws_size,
                              hipStream_t stream) {
    const float* eattr = (const float*)d_in[0];
    const int* edge_index = (const int*)d_in[1];
    const int* startp = (const int*)d_in[2];
    const int E = in_sizes[0] / 4;   // 640000
    const int N = E / DEG;           // 20000
    const int* dst = edge_index + E; // row 1 of [2, E]

    char* ws = (char*)d_ws;
    int* nbr = (int*)ws;            ws += (size_t)E * 4;
    int* eidx = (int*)ws;           ws += (size_t)E * 4;
    int* queue = (int*)ws;          ws += (size_t)N * 4;
    int* visited = (int*)ws;        ws += (size_t)N * 4;
    int* claim = (int*)ws;          ws += (size_t)N * 4;
    int* offs = (int*)ws;           ws += (size_t)N * 4;
    unsigned int* state = (unsigned int*)ws; ws += (size_t)BLOCKS * 4;
    int* ctrl = (int*)ws;           ws += 64;

    sort_edges_kernel<<<dim3((E + 255) / 256), dim3(256), 0, stream>>>(
        eattr, dst, nbr, eidx, E);

    float* out = (float*)d_out;
    void* args[] = {(void*)&eattr, (void*)&nbr,    (void*)&eidx,  (void*)&queue,
                    (void*)&visited, (void*)&claim, (void*)&offs,  (void*)&state,
                    (void*)&ctrl,  (void*)&out,    (void*)&startp, (void*)&N};
    (void)hipLaunchCooperativeKernel((void*)bfs_kernel, dim3(BLOCKS),
                                     dim3(THREADS), args, 0, stream);
}

// Round 8
// 294.162 us; speedup vs baseline: 2.1280x; 2.1280x over previous
//
#include <hip/hip_runtime.h>
#include <hip/hip_cooperative_groups.h>

namespace cg = cooperative_groups;

constexpr int DEG = 32;
constexpr int BLOCKS = 64;     // == wavefront size; enables wave-parallel scan exchange
constexpr int THREADS = 256;
constexpr int SOLO_MAX = 64;   // frontier sizes handled by block 0 alone

// ---------------------------------------------------------------------------
// Per-source-node stable sort of the 32 outgoing edges by rotation error.
// Replicates lexsort((err, src)) — src blocks contiguous, stable tie-break.
// ---------------------------------------------------------------------------
__global__ void sort_edges_kernel(const float* __restrict__ eattr,
                                  const int* __restrict__ dst,
                                  int* __restrict__ nbr,
                                  int* __restrict__ eidx,
                                  int E) {
    __shared__ float serr[256];
    int e = blockIdx.x * 256 + threadIdx.x;
    float err = 1e30f;
    if (e < E) {
        float w = fabsf(eattr[e * 4 + 0]);
        w = fminf(w, 1.0f);
        float a = acosf(w);
        err = 2.0f * (a * 57.29577951308232f);
    }
    serr[threadIdx.x] = err;
    __syncthreads();
    if (e < E) {
        int s = e & (DEG - 1);
        int base = (int)threadIdx.x - s;
        int rank = 0;
        for (int t = 0; t < DEG; ++t) {
            float et = serr[base + t];
            rank += (int)((et < err) || (et == err && t < s));
        }
        int u = e >> 5;
        nbr[(u << 5) + rank] = dst[e];
        eidx[(u << 5) + rank] = e;
    }
}

// Coherent (L1-bypassing) read of a claim word. Needed wherever an atomicMin
// and a read of the same location sit in the same sync region: CDNA atomics
// update L2 only, and __syncthreads does NOT invalidate L1 (grid.sync does).
__device__ __forceinline__ int claim_ld(const int* p) {
    return __hip_atomic_load(p, __ATOMIC_RELAXED, __HIP_MEMORY_SCOPE_AGENT);
}

// ---------------------------------------------------------------------------
// Level-synchronous BFS, exact sequential semantics via claim key
// (parent_queue_pos<<5)|slot + in-order append.
//  - F <= SOLO_MAX: block 0 chews levels alone, 1 grid sync per burst.
//  - else 2 grid syncs/level: [claims] sync [wins+exchange-scan+append] sync.
//    Cross-block scan = wave-parallel all-to-all (lane l polls state[l]),
//    O(1) serial depth — replaces R6's serial lookback chain.
// ---------------------------------------------------------------------------
__global__ void __launch_bounds__(THREADS)
bfs_kernel(const float* __restrict__ eattr,
           const int* __restrict__ nbr,
           const int* __restrict__ eidx,
           int* __restrict__ queue,
           int* __restrict__ visited,
           int* __restrict__ claim,
           int* __restrict__ offs,
           int* __restrict__ wmask,           // winner bitmask per frontier node
           unsigned int* __restrict__ state,  // aggregate slot, one per block
           int* __restrict__ ctrl,            // [1]=head, [2]=tail (solo burst)
           float* __restrict__ out,           // [0]=start, [1..]=quat[N][4]
           const int* __restrict__ startp,
           int N) {
    cg::grid_group grid = cg::this_grid();
    const int tid = blockIdx.x * blockDim.x + threadIdx.x;
    const int T = gridDim.x * blockDim.x;
    float* quat = out + 1;
    const int start = *startp;

    __shared__ int s_wsum[THREADS / 64];
    __shared__ int s_wbase[THREADS / 64];
    __shared__ int s_carry;
    __shared__ int s_excl;
    __shared__ int s_total;

    // init (everything is re-poisoned before every launch)
    for (int v = tid; v < N; v += T) {
        visited[v] = (v == start) ? 1 : 0;
        claim[v] = 0x7FFFFFFF;
        quat[4 * v + 0] = 1.0f;
        quat[4 * v + 1] = 0.0f;
        quat[4 * v + 2] = 0.0f;
        quat[4 * v + 3] = 0.0f;
    }
    if (tid == 0) {
        queue[0] = start;
        out[0] = (float)start;
    }
    grid.sync();

    int head = 0, tail = 1;
    while (head < tail) {
        const int F = tail - head;

        if (F <= SOLO_MAX) {
            // ---- solo burst: block 0 processes levels until F grows ----
            if (blockIdx.x == 0) {
                int h = head, t = tail;
                while (h < t && (t - h) <= SOLO_MAX) {
                    const int Fb = t - h;
                    for (int e = threadIdx.x; e < Fb * DEG; e += THREADS) {
                        int p = h + (e >> 5), s = e & 31;
                        int u = queue[p];
                        int v = nbr[(u << 5) + s];
                        if (!visited[v]) atomicMin(&claim[v], (p << 5) + s);
                    }
                    __syncthreads();
                    int my_c = 0;
                    if ((int)threadIdx.x < Fb) {
                        int p = h + (int)threadIdx.x, u = queue[p];
                        for (int s = 0; s < DEG; ++s) {
                            int v = nbr[(u << 5) + s];
                            if (!visited[v] && claim_ld(&claim[v]) == ((p << 5) + s)) my_c++;
                        }
                    }
                    int incl = my_c;
                    for (int d = 1; d < 64; d <<= 1) {
                        int tt = __shfl_up(incl, d, 64);
                        if ((threadIdx.x & 63) >= (unsigned)d) incl += tt;
                    }
                    if (threadIdx.x == 63) s_total = incl;
                    __syncthreads();
                    int total = s_total;
                    if ((int)threadIdx.x < Fb) {
                        int i = threadIdx.x;
                        int p = h + i, u = queue[p];
                        int pos = t + (incl - my_c);
                        float pw = quat[4 * u + 0], px = quat[4 * u + 1];
                        float py = quat[4 * u + 2], pz = quat[4 * u + 3];
                        for (int s = 0; s < DEG; ++s) {
                            int v = nbr[(u << 5) + s];
                            if (!visited[v] && claim_ld(&claim[v]) == ((p << 5) + s)) {
                                int eo = eidx[(u << 5) + s];
                                float qw = eattr[4 * eo + 0];
                                float qx = -eattr[4 * eo + 1];
                                float qy = -eattr[4 * eo + 2];
                                float qz = -eattr[4 * eo + 3];
                                quat[4 * v + 0] = qw * pw - qx * px - qy * py - qz * pz;
                                quat[4 * v + 1] = qw * px + qx * pw + qy * pz - qz * py;
                                quat[4 * v + 2] = qw * py - qx * pz + qy * pw + qz * px;
                                quat[4 * v + 3] = qw * pz + qx * py - qy * px + qz * pw;
                                visited[v] = 1;
                                queue[pos++] = v;
                            }
                        }
                    }
                    __syncthreads();
                    h = t;
                    t += total;
                }
                if (threadIdx.x == 0) { ctrl[1] = h; ctrl[2] = t; }
            }
            grid.sync();
            head = ctrl[1];
            tail = ctrl[2];
        } else {
            // ---- grid level, 2 syncs ----
            // pass 1: claims, unroll x4 for memory-level parallelism
            if (threadIdx.x == 0) state[blockIdx.x] = 0u;
            {
                const int EDG = F * DEG;
                for (int e = tid; e < EDG; e += 4 * T) {
                    int ee[4];
                    bool ok[4];
                    int u[4], v[4], vis[4];
                    #pragma unroll
                    for (int k = 0; k < 4; ++k) {
                        ee[k] = e + k * T;
                        ok[k] = ee[k] < EDG;
                        u[k] = ok[k] ? queue[head + (ee[k] >> 5)] : 0;
                    }
                    #pragma unroll
                    for (int k = 0; k < 4; ++k)
                        v[k] = ok[k] ? nbr[(u[k] << 5) + (ee[k] & 31)] : 0;
                    #pragma unroll
                    for (int k = 0; k < 4; ++k)
                        vis[k] = ok[k] ? visited[v[k]] : 1;
                    #pragma unroll
                    for (int k = 0; k < 4; ++k)
                        if (ok[k] && !vis[k])
                            atomicMin(&claim[v[k]],
                                      ((head + (ee[k] >> 5)) << 5) + (ee[k] & 31));
                }
            }
            grid.sync();

            // pass 2 (fused region): wins via batched gathers + block scan
            const int CH = (F + BLOCKS - 1) / BLOCKS;
            const int c0 = blockIdx.x * CH;
            const int c1 = min(F, c0 + CH);
            if (threadIdx.x == 0) s_carry = 0;
            __syncthreads();
            for (int base = c0; base < c1; base += THREADS) {
                int i = base + (int)threadIdx.x;
                int x = 0, mask = 0;
                if (i < c1) {
                    int p = head + i, u = queue[p];
                    const int4* row = (const int4*)&nbr[u << 5];
                    int vv[32];
                    #pragma unroll
                    for (int r = 0; r < 8; ++r) {
                        int4 q4 = row[r];
                        vv[4 * r + 0] = q4.x; vv[4 * r + 1] = q4.y;
                        vv[4 * r + 2] = q4.z; vv[4 * r + 3] = q4.w;
                    }
                    int vis[32], cl[32];
                    #pragma unroll
                    for (int s = 0; s < 32; ++s) vis[s] = visited[vv[s]];
                    #pragma unroll
                    for (int s = 0; s < 32; ++s) cl[s] = claim[vv[s]];
                    #pragma unroll
                    for (int s = 0; s < 32; ++s) {
                        if (!vis[s] && cl[s] == ((p << 5) + s)) { mask |= 1 << s; x++; }
                    }
                    wmask[i] = mask;
                }
                int lane = threadIdx.x & 63, wid = threadIdx.x >> 6;
                int incl = x;
                for (int d = 1; d < 64; d <<= 1) {
                    int tt = __shfl_up(incl, d, 64);
                    if (lane >= d) incl += tt;
                }
                if (lane == 63) s_wsum[wid] = incl;
                __syncthreads();
                if (threadIdx.x == 0) {
                    int acc = s_carry;
                    for (int w = 0; w < THREADS / 64; ++w) {
                        s_wbase[w] = acc;
                        acc += s_wsum[w];
                    }
                    s_carry = acc;
                }
                __syncthreads();
                if (i < c1) offs[i] = s_wbase[wid] + incl - x;
                __syncthreads();
            }
            const int agg = s_carry;

            // wave-parallel all-to-all exchange (O(1) serial depth)
            if (threadIdx.x == 0)
                __hip_atomic_store(&state[blockIdx.x], 0x80000000u | (unsigned)agg,
                                   __ATOMIC_RELEASE, __HIP_MEMORY_SCOPE_AGENT);
            if (threadIdx.x < 64) {
                unsigned sv;
                do {
                    sv = __hip_atomic_load(&state[threadIdx.x], __ATOMIC_ACQUIRE,
                                           __HIP_MEMORY_SCOPE_AGENT);
                } while (!(sv & 0x80000000u));
                int a = (int)(sv & 0x3FFFFFFFu);
                int incl = a;
                for (int d = 1; d < 64; d <<= 1) {
                    int tt = __shfl_up(incl, d, 64);
                    if ((int)(threadIdx.x & 63) >= d) incl += tt;
                }
                int myincl = __shfl(incl, (int)blockIdx.x, 64);
                int mya = __shfl(a, (int)blockIdx.x, 64);
                int tot = __shfl(incl, 63, 64);
                if (threadIdx.x == 0) { s_excl = myincl - mya; s_total = tot; }
            }
            __syncthreads();
            const int excl = s_excl;
            const int total = s_total;

            // pass 3: winners (from mask) write quat/visited, append in order
            for (int i = c0 + (int)threadIdx.x; i < c1; i += THREADS) {
                int mask = wmask[i];
                if (mask == 0) continue;
                int p = head + i, u = queue[p];
                int pos = tail + excl + offs[i];
                float pw = quat[4 * u + 0], px = quat[4 * u + 1];
                float py = quat[4 * u + 2], pz = quat[4 * u + 3];
                while (mask) {
                    int s = __ffs(mask) - 1;
                    mask &= mask - 1;
                    int v = nbr[(u << 5) + s];
                    int eo = eidx[(u << 5) + s];
                    float qw = eattr[4 * eo + 0];
                    float qx = -eattr[4 * eo + 1];
                    float qy = -eattr[4 * eo + 2];
                    float qz = -eattr[4 * eo + 3];
                    quat[4 * v + 0] = qw * pw - qx * px - qy * py - qz * pz;
                    quat[4 * v + 1] = qw * px + qx * pw + qy * pz - qz * py;
                    quat[4 * v + 2] = qw * py - qx * pz + qy * pw + qz * px;
                    quat[4 * v + 3] = qw * pz + qx * py - qy * px + qz * pw;
                    visited[v] = 1;
                    queue[pos++] = v;
                }
            }
            grid.sync();
            head = tail;
            tail += total;
        }
    }
}

extern "C" void kernel_launch(void* const* d_in, const int* in_sizes, int n_in,
                              void* d_out, int out_size, void* d_ws, size_t ws_size,
                              hipStream_t stream) {
    const float* eattr = (const float*)d_in[0];
    const int* edge_index = (const int*)d_in[1];
    const int* startp = (const int*)d_in[2];
    const int E = in_sizes[0] / 4;   // 640000
    const int N = E / DEG;           // 20000
    const int* dst = edge_index + E; // row 1 of [2, E]

    char* ws = (char*)d_ws;
    int* nbr = (int*)ws;            ws += (size_t)E * 4;
    int* eidx = (int*)ws;           ws += (size_t)E * 4;
    int* queue = (int*)ws;          ws += (size_t)N * 4;
    int* visited = (int*)ws;        ws += (size_t)N * 4;
    int* claim = (int*)ws;          ws += (size_t)N * 4;
    int* offs = (int*)ws;           ws += (size_t)N * 4;
    int* wmask = (int*)ws;          ws += (size_t)N * 4;
    unsigned int* state = (unsigned int*)ws; ws += (size_t)BLOCKS * 4;
    int* ctrl = (int*)ws;           ws += 64;

    sort_edges_kernel<<<dim3((E + 255) / 256), dim3(256), 0, stream>>>(
        eattr, dst, nbr, eidx, E);

    float* out = (float*)d_out;
    void* args[] = {(void*)&eattr, (void*)&nbr,    (void*)&eidx,  (void*)&queue,
                    (void*)&visited, (void*)&claim, (void*)&offs,  (void*)&wmask,
                    (void*)&state, (void*)&ctrl,   (void*)&out,   (void*)&startp,
                    (void*)&N};
    (void)hipLaunchCooperativeKernel((void*)bfs_kernel, dim3(BLOCKS),
                                     dim3(THREADS), args, 0, stream);
}